// Round 25
// baseline (49.145 us; speedup 1.0000x reference)
//
#include <hip/hip_runtime.h>

typedef short short8 __attribute__((ext_vector_type(8)));
typedef float f32x16 __attribute__((ext_vector_type(16)));

#define NPTS 4096
#define NB   32
#define S    2        // pinned 32-point strips per wave
#define NT   (NPTS / 32)       // 128 scan units (full B per block)
#define SCALE (1.0f / 131072.0f)   // 1/(NB*NPTS)

// ---- bf16 split helpers (round-to-nearest-even) ----
__device__ inline unsigned short bf16_rne(float v) {
    unsigned u = __float_as_uint(v);
    unsigned r = u + 0x7FFFu + ((u >> 16) & 1u);
    return (unsigned short)(r >> 16);
}
__device__ inline float bf16_to_f(unsigned short h) {
    return __uint_as_float(((unsigned)h) << 16);
}
__device__ inline void bf_split(float v, unsigned short& h, unsigned short& l) {
    h = bf16_rne(v);
    l = bf16_rne(v - bf16_to_f(h));
}

// ---- pre-pass: pack records; zero d_out ----
__global__ __launch_bounds__(256) void pack_kernel(
    const float* __restrict__ points, const float* __restrict__ gts,
    unsigned short* __restrict__ pk, float* __restrict__ outp)
{
    const int tid = blockIdx.x * 256 + threadIdx.x;   // 0 .. 262143
    if (tid < 3) outp[tid] = 0.0f;                    // reduce accumulates
    const int c   = tid >> 17;                        // cloud
    const int rem = tid & 131071;                     // b*4096 + j
    const float* src = (c ? gts : points) + (size_t)rem * 3;
    const float x = src[0], y = src[1], z = src[2];
    const float hb = x * x + y * y + z * z;
    unsigned short xh, xl, yh, yl, zh, zl, hh, hl;
    bf_split(x, xh, xl); bf_split(y, yh, yl);
    bf_split(z, zh, zl); bf_split(hb, hh, hl);
    const unsigned short ONE = 0x3F80;
    unsigned short r[16] = { xh, yh, zh, ONE, hh,
                             xl, yl, zl, 0,   hl,
                             xh, yh, zh, ONE, hh, 0 };
    int4* dst = (int4*)(pk + (size_t)tid * 16);
    int4 w0, w1;
    w0.x = r[0] | (r[1] << 16);  w0.y = r[2]  | (r[3]  << 16);
    w0.z = r[4] | (r[5] << 16);  w0.w = r[6]  | (r[7]  << 16);
    w1.x = r[8] | (r[9] << 16);  w1.y = r[10] | (r[11] << 16);
    w1.z = r[12]| (r[13]<< 16);  w1.w = r[14] | (r[15] << 16);
    dst[0] = w0; dst[1] = w1;
}

// ---- main: full-B MFMA scan; static 3-buffer pipeline, fused asm unit ----
__global__ __launch_bounds__(256, 4) void chamfer_main(
    const float* __restrict__ points, const float* __restrict__ gts,
    const unsigned short* __restrict__ pk, float* __restrict__ mins)
{
    const int d      = blockIdx.x;        // 0..1023
    const int group  = d & 63;            // (dir,b) — members share XCD (mod 8)
    const int member = d >> 6;            // A-chunk 0..15 (256 points each)
    const int dir = group >> 5;
    const int b   = group & 31;

    const float* Ab = (dir ? gts : points) + (size_t)b * NPTS * 3;
    const int w = threadIdx.x >> 6, l = threadIdx.x & 63;
    const int half = l >> 5, c = l & 31;

    // pinned fragments (mfma B operand) — packing identical to verified R5..R24
    short8 af[S];
    #pragma unroll
    for (int s = 0; s < S; ++s) {
        const int i = member * 256 + w * 64 + s * 32 + c;
        const float ax = Ab[i * 3 + 0], ay = Ab[i * 3 + 1], az = Ab[i * 3 + 2];
        const float ha = ax * ax + ay * ay + az * az;
        unsigned short xh, xl, yh, yl, zh, zl, hh, hl;
        bf_split(-2.f * ax, xh, xl);
        bf_split(-2.f * ay, yh, yl);
        bf_split(-2.f * az, zh, zl);
        bf_split(ha, hh, hl);
        const unsigned short ONE = 0x3F80;
        short8 f;
        if (half == 0) {
            f[0]=(short)xh; f[1]=(short)yh; f[2]=(short)zh; f[3]=(short)hh;
            f[4]=(short)ONE; f[5]=(short)xh; f[6]=(short)yh; f[7]=(short)zh;
        } else {
            f[0]=(short)hh; f[1]=(short)ONE; f[2]=(short)xl; f[3]=(short)yl;
            f[4]=(short)zl; f[5]=(short)hl; f[6]=0; f[7]=0;
        }
        af[s] = f;
    }

    // streamed records: the FULL B cloud for this (dir,b)
    const unsigned short* rec =
        pk + (((size_t)(dir ^ 1) * NB + b) * NPTS + (size_t)c) * 16 + half * 8;

    float mm[S] = {1e30f, 1e30f};

#define TREE(A, MM)                                                            \
    {                                                                          \
        const float t0 = fminf(fminf((A)[0],  (A)[1]),  (A)[2]);               \
        const float t1 = fminf(fminf((A)[3],  (A)[4]),  (A)[5]);               \
        const float t2 = fminf(fminf((A)[6],  (A)[7]),  (A)[8]);               \
        const float t3 = fminf(fminf((A)[9],  (A)[10]), (A)[11]);              \
        const float t4 = fminf(fminf((A)[12], (A)[13]), (A)[14]);              \
        const float u0 = fminf(fminf(t0, t1), t2);                             \
        const float u1 = fminf(fminf(t3, t4), (A)[15]);                        \
        (MM) = fminf(fminf((MM), u0), u1);                                     \
    }

    // Both MFMAs in ONE asm block, inline-constant C=0, one shared 40-state
    // nop group (R24-verified sufficient). Trees consume in-iteration.
#define UNIT(REG)                                                              \
    {                                                                          \
        f32x16 a0, a1;                                                         \
        asm volatile(                                                          \
            "v_mfma_f32_32x32x16_bf16 %0, %2, %3, 0\n\t"                       \
            "v_mfma_f32_32x32x16_bf16 %1, %2, %4, 0\n\t"                       \
            "s_nop 7\n\t"                                                      \
            "s_nop 7\n\t"                                                      \
            "s_nop 7\n\t"                                                      \
            "s_nop 7\n\t"                                                      \
            "s_nop 7"                                                          \
            : "=&v"(a0), "=&v"(a1)                                             \
            : "v"(REG), "v"(af[0]), "v"(af[1]));                               \
        TREE(a0, mm[0])                                                        \
        TREE(a1, mm[1])                                                        \
        __builtin_amdgcn_sched_barrier(0);                                     \
    }

#define LD(I) (*(const short8*)(rec + (size_t)((I) < NT ? (I) : NT - 1) * 512))

    // static 3-buffer, 3-deep prefetch: zero rotation movs by construction
    short8 b0 = LD(0);
    short8 b1 = LD(1);
    short8 b2 = LD(2);

    #pragma unroll 1
    for (int t = 0; t < NT - 2; t += 3) {
        UNIT(b0) b0 = LD(t + 3);
        UNIT(b1) b1 = LD(t + 4);
        UNIT(b2) b2 = LD(t + 5);
    }
    // tail: units NT-2, NT-1 (loop covered 0..NT-3)
    UNIT(b0)
    UNIT(b1)
#undef LD
#undef UNIT
#undef TREE

    // combine halves, clamp, plain store (single writer per a-point)
    #pragma unroll
    for (int s = 0; s < S; ++s) {
        float v = fminf(mm[s], __shfl_xor(mm[s], 32));
        v = fmaxf(v, 0.f);
        if (half == 0) {
            const int ap = member * 256 + w * 64 + s * 32 + c;
            mins[(size_t)group * NPTS + ap] = v;
        }
    }
}

// ---- pass 2: one block per (dir,b) group; 128 total d_out atomics ----
__global__ __launch_bounds__(256) void reduce_kernel(
    const float* __restrict__ mins, float* __restrict__ outp)
{
    const int group = blockIdx.x;          // 0..63
    const int dir   = group >> 5;
    const float* gm = mins + (size_t)group * NPTS;

    float local = 0.f;
    #pragma unroll
    for (int i = 0; i < NPTS / 256; ++i)
        local += sqrtf(gm[threadIdx.x + i * 256]);

    for (int off = 32; off > 0; off >>= 1)
        local += __shfl_down(local, off);
    __shared__ float wsum[4];
    const int w = threadIdx.x >> 6, l = threadIdx.x & 63;
    if (l == 0) wsum[w] = local;
    __syncthreads();
    if (threadIdx.x == 0) {
        const float s = (wsum[0] + wsum[1] + wsum[2] + wsum[3]) * SCALE;
        atomicAdd(&outp[0], s);          // p2g + g2p
        atomicAdd(&outp[1 + dir], s);    // out[1]=p2g, out[2]=g2p
    }
}

extern "C" void kernel_launch(void* const* d_in, const int* in_sizes, int n_in,
                              void* d_out, int out_size, void* d_ws, size_t ws_size,
                              hipStream_t stream) {
    const float* points = (const float*)d_in[0];   // [32][4096][3]
    const float* gts    = (const float*)d_in[1];   // [32][4096][3]
    float* outp = (float*)d_out;

    unsigned short* packed = (unsigned short*)((char*)d_ws + 64);   // 8 MB
    float* mins = (float*)((char*)d_ws + 64 + 8388608);             // 1 MB

    pack_kernel<<<1024, 256, 0, stream>>>(points, gts, packed, outp);
    chamfer_main<<<1024, 256, 0, stream>>>(points, gts, packed, mins);
    reduce_kernel<<<64, 256, 0, stream>>>(mins, outp);
}

// Round 26
// 48.886 us; speedup vs baseline: 1.0053x; 1.0053x over previous
//
#include <hip/hip_runtime.h>

typedef short short8 __attribute__((ext_vector_type(8)));
typedef float f32x16 __attribute__((ext_vector_type(16)));

#define NPTS 4096
#define NB   32
#define S    2        // pinned 32-point strips per wave
#define NT   (NPTS / 32)       // 128 scan units (full B per block)
#define SCALE (1.0f / 131072.0f)   // 1/(NB*NPTS)

// ---- bf16 split helpers (round-to-nearest-even) ----
__device__ inline unsigned short bf16_rne(float v) {
    unsigned u = __float_as_uint(v);
    unsigned r = u + 0x7FFFu + ((u >> 16) & 1u);
    return (unsigned short)(r >> 16);
}
__device__ inline float bf16_to_f(unsigned short h) {
    return __uint_as_float(((unsigned)h) << 16);
}
__device__ inline void bf_split(float v, unsigned short& h, unsigned short& l) {
    h = bf16_rne(v);
    l = bf16_rne(v - bf16_to_f(h));
}

// ---- pre-pass: pack records; zero d_out ----
__global__ __launch_bounds__(256) void pack_kernel(
    const float* __restrict__ points, const float* __restrict__ gts,
    unsigned short* __restrict__ pk, float* __restrict__ outp)
{
    const int tid = blockIdx.x * 256 + threadIdx.x;   // 0 .. 262143
    if (tid < 3) outp[tid] = 0.0f;                    // reduce accumulates
    const int c   = tid >> 17;                        // cloud
    const int rem = tid & 131071;                     // b*4096 + j
    const float* src = (c ? gts : points) + (size_t)rem * 3;
    const float x = src[0], y = src[1], z = src[2];
    const float hb = x * x + y * y + z * z;
    unsigned short xh, xl, yh, yl, zh, zl, hh, hl;
    bf_split(x, xh, xl); bf_split(y, yh, yl);
    bf_split(z, zh, zl); bf_split(hb, hh, hl);
    const unsigned short ONE = 0x3F80;
    unsigned short r[16] = { xh, yh, zh, ONE, hh,
                             xl, yl, zl, 0,   hl,
                             xh, yh, zh, ONE, hh, 0 };
    int4* dst = (int4*)(pk + (size_t)tid * 16);
    int4 w0, w1;
    w0.x = r[0] | (r[1] << 16);  w0.y = r[2]  | (r[3]  << 16);
    w0.z = r[4] | (r[5] << 16);  w0.w = r[6]  | (r[7]  << 16);
    w1.x = r[8] | (r[9] << 16);  w1.y = r[10] | (r[11] << 16);
    w1.z = r[12]| (r[13]<< 16);  w1.w = r[14] | (r[15] << 16);
    dst[0] = w0; dst[1] = w1;
}

// ---- main: full-B MFMA scan; asm MFMA + explicit v_min3 trees ----
__global__ __launch_bounds__(256, 4) void chamfer_main(
    const float* __restrict__ points, const float* __restrict__ gts,
    const unsigned short* __restrict__ pk, float* __restrict__ mins)
{
    const int d      = blockIdx.x;        // 0..1023
    const int group  = d & 63;            // (dir,b) — members share XCD (mod 8)
    const int member = d >> 6;            // A-chunk 0..15 (256 points each)
    const int dir = group >> 5;
    const int b   = group & 31;

    const float* Ab = (dir ? gts : points) + (size_t)b * NPTS * 3;
    const int w = threadIdx.x >> 6, l = threadIdx.x & 63;
    const int half = l >> 5, c = l & 31;

    // pinned fragments (mfma B operand) — packing identical to verified R5..R25
    short8 af[S];
    #pragma unroll
    for (int s = 0; s < S; ++s) {
        const int i = member * 256 + w * 64 + s * 32 + c;
        const float ax = Ab[i * 3 + 0], ay = Ab[i * 3 + 1], az = Ab[i * 3 + 2];
        const float ha = ax * ax + ay * ay + az * az;
        unsigned short xh, xl, yh, yl, zh, zl, hh, hl;
        bf_split(-2.f * ax, xh, xl);
        bf_split(-2.f * ay, yh, yl);
        bf_split(-2.f * az, zh, zl);
        bf_split(ha, hh, hl);
        const unsigned short ONE = 0x3F80;
        short8 f;
        if (half == 0) {
            f[0]=(short)xh; f[1]=(short)yh; f[2]=(short)zh; f[3]=(short)hh;
            f[4]=(short)ONE; f[5]=(short)xh; f[6]=(short)yh; f[7]=(short)zh;
        } else {
            f[0]=(short)hh; f[1]=(short)ONE; f[2]=(short)xl; f[3]=(short)yl;
            f[4]=(short)zl; f[5]=(short)hl; f[6]=0; f[7]=0;
        }
        af[s] = f;
    }

    // streamed records: the FULL B cloud for this (dir,b)
    const unsigned short* rec =
        pk + (((size_t)(dir ^ 1) * NB + b) * NPTS + (size_t)c) * 16 + half * 8;

    float mm[S] = {1e30f, 1e30f};

    // Explicit v_min3 tree: 8 instr per 16-value tree (R3/R4-proven pattern:
    // asm min3 on plain-VGPR inputs). Inputs come from my own asm MFMA block
    // with hazard nops already inside -> no intrinsic-MFMA/asm interaction.
#define TREE3(A, MM)                                                           \
    {                                                                          \
        float t0, t1, t2, t3, t4, u0, u1;                                      \
        asm("v_min3_f32 %0, %1, %2, %3" : "=v"(t0)                             \
            : "v"((A)[0]),  "v"((A)[1]),  "v"((A)[2]));                        \
        asm("v_min3_f32 %0, %1, %2, %3" : "=v"(t1)                             \
            : "v"((A)[3]),  "v"((A)[4]),  "v"((A)[5]));                        \
        asm("v_min3_f32 %0, %1, %2, %3" : "=v"(t2)                             \
            : "v"((A)[6]),  "v"((A)[7]),  "v"((A)[8]));                        \
        asm("v_min3_f32 %0, %1, %2, %3" : "=v"(t3)                             \
            : "v"((A)[9]),  "v"((A)[10]), "v"((A)[11]));                       \
        asm("v_min3_f32 %0, %1, %2, %3" : "=v"(t4)                             \
            : "v"((A)[12]), "v"((A)[13]), "v"((A)[14]));                       \
        asm("v_min3_f32 %0, %1, %2, %3" : "=v"(u0)                             \
            : "v"(t0), "v"(t1), "v"(t2));                                      \
        asm("v_min3_f32 %0, %1, %2, %3" : "=v"(u1)                             \
            : "v"(t3), "v"(t4), "v"((A)[15]));                                 \
        asm("v_min3_f32 %0, %0, %1, %2" : "+v"(MM)                             \
            : "v"(u0), "v"(u1));                                               \
    }

    // Both MFMAs in ONE asm block, inline-constant C=0, one shared 40-state
    // nop group (R24/R25-verified hazard margin).
#define UNIT(REG)                                                              \
    {                                                                          \
        f32x16 a0, a1;                                                         \
        asm volatile(                                                          \
            "v_mfma_f32_32x32x16_bf16 %0, %2, %3, 0\n\t"                       \
            "v_mfma_f32_32x32x16_bf16 %1, %2, %4, 0\n\t"                       \
            "s_nop 7\n\t"                                                      \
            "s_nop 7\n\t"                                                      \
            "s_nop 7\n\t"                                                      \
            "s_nop 7\n\t"                                                      \
            "s_nop 7"                                                          \
            : "=&v"(a0), "=&v"(a1)                                             \
            : "v"(REG), "v"(af[0]), "v"(af[1]));                               \
        TREE3(a0, mm[0])                                                       \
        TREE3(a1, mm[1])                                                       \
        __builtin_amdgcn_sched_barrier(0);                                     \
    }

#define LD(I) (*(const short8*)(rec + (size_t)((I) < NT ? (I) : NT - 1) * 512))

    // static 3-buffer, 3-deep prefetch: zero rotation movs by construction
    short8 b0 = LD(0);
    short8 b1 = LD(1);
    short8 b2 = LD(2);

    #pragma unroll 1
    for (int t = 0; t < NT - 2; t += 3) {
        UNIT(b0) b0 = LD(t + 3);
        UNIT(b1) b1 = LD(t + 4);
        UNIT(b2) b2 = LD(t + 5);
    }
    // tail: units NT-2, NT-1 (loop covered 0..NT-3)
    UNIT(b0)
    UNIT(b1)
#undef LD
#undef UNIT
#undef TREE3

    // combine halves, clamp, plain store (single writer per a-point)
    #pragma unroll
    for (int s = 0; s < S; ++s) {
        float v = fminf(mm[s], __shfl_xor(mm[s], 32));
        v = fmaxf(v, 0.f);
        if (half == 0) {
            const int ap = member * 256 + w * 64 + s * 32 + c;
            mins[(size_t)group * NPTS + ap] = v;
        }
    }
}

// ---- pass 2: one block per (dir,b) group; 128 total d_out atomics ----
__global__ __launch_bounds__(256) void reduce_kernel(
    const float* __restrict__ mins, float* __restrict__ outp)
{
    const int group = blockIdx.x;          // 0..63
    const int dir   = group >> 5;
    const float* gm = mins + (size_t)group * NPTS;

    float local = 0.f;
    #pragma unroll
    for (int i = 0; i < NPTS / 256; ++i)
        local += sqrtf(gm[threadIdx.x + i * 256]);

    for (int off = 32; off > 0; off >>= 1)
        local += __shfl_down(local, off);
    __shared__ float wsum[4];
    const int w = threadIdx.x >> 6, l = threadIdx.x & 63;
    if (l == 0) wsum[w] = local;
    __syncthreads();
    if (threadIdx.x == 0) {
        const float s = (wsum[0] + wsum[1] + wsum[2] + wsum[3]) * SCALE;
        atomicAdd(&outp[0], s);          // p2g + g2p
        atomicAdd(&outp[1 + dir], s);    // out[1]=p2g, out[2]=g2p
    }
}

extern "C" void kernel_launch(void* const* d_in, const int* in_sizes, int n_in,
                              void* d_out, int out_size, void* d_ws, size_t ws_size,
                              hipStream_t stream) {
    const float* points = (const float*)d_in[0];   // [32][4096][3]
    const float* gts    = (const float*)d_in[1];   // [32][4096][3]
    float* outp = (float*)d_out;

    unsigned short* packed = (unsigned short*)((char*)d_ws + 64);   // 8 MB
    float* mins = (float*)((char*)d_ws + 64 + 8388608);             // 1 MB

    pack_kernel<<<1024, 256, 0, stream>>>(points, gts, packed, outp);
    chamfer_main<<<1024, 256, 0, stream>>>(points, gts, packed, mins);
    reduce_kernel<<<64, 256, 0, stream>>>(mins, outp);
}

// Round 27
// 48.062 us; speedup vs baseline: 1.0225x; 1.0171x over previous
//
#include <hip/hip_runtime.h>

typedef short short8 __attribute__((ext_vector_type(8)));
typedef float f32x16 __attribute__((ext_vector_type(16)));

#define NPTS 4096
#define NB   32
#define S    4        // pinned 32-point strips per wave (fused asm unit)
#define CHUNKS 2
#define BPTS (NPTS / CHUNKS)   // 2048 B-points per block
#define NT   (BPTS / 32)       // 64 scan units
#define SCALE (1.0f / 131072.0f)   // 1/(NB*NPTS)

// ---- bf16 split helpers (round-to-nearest-even) ----
__device__ inline unsigned short bf16_rne(float v) {
    unsigned u = __float_as_uint(v);
    unsigned r = u + 0x7FFFu + ((u >> 16) & 1u);
    return (unsigned short)(r >> 16);
}
__device__ inline float bf16_to_f(unsigned short h) {
    return __uint_as_float(((unsigned)h) << 16);
}
__device__ inline void bf_split(float v, unsigned short& h, unsigned short& l) {
    h = bf16_rne(v);
    l = bf16_rne(v - bf16_to_f(h));
}

// ---- pre-pass: pack records; init mins; zero d_out ----
__global__ __launch_bounds__(256) void pack_kernel(
    const float* __restrict__ points, const float* __restrict__ gts,
    unsigned short* __restrict__ pk, unsigned* __restrict__ minsInit,
    float* __restrict__ outp)
{
    const int tid = blockIdx.x * 256 + threadIdx.x;   // 0 .. 262143
    if (tid < 3) outp[tid] = 0.0f;                    // reduce accumulates
    const int c   = tid >> 17;                        // cloud
    const int rem = tid & 131071;                     // b*4096 + j
    const float* src = (c ? gts : points) + (size_t)rem * 3;
    const float x = src[0], y = src[1], z = src[2];
    const float hb = x * x + y * y + z * z;
    unsigned short xh, xl, yh, yl, zh, zl, hh, hl;
    bf_split(x, xh, xl); bf_split(y, yh, yl);
    bf_split(z, zh, zl); bf_split(hb, hh, hl);
    const unsigned short ONE = 0x3F80;
    unsigned short r[16] = { xh, yh, zh, ONE, hh,
                             xl, yl, zl, 0,   hl,
                             xh, yh, zh, ONE, hh, 0 };
    int4* dst = (int4*)(pk + (size_t)tid * 16);
    int4 w0, w1;
    w0.x = r[0] | (r[1] << 16);  w0.y = r[2]  | (r[3]  << 16);
    w0.z = r[4] | (r[5] << 16);  w0.w = r[6]  | (r[7]  << 16);
    w1.x = r[8] | (r[9] << 16);  w1.y = r[10] | (r[11] << 16);
    w1.z = r[12]| (r[13]<< 16);  w1.w = r[14] | (r[15] << 16);
    dst[0] = w0; dst[1] = w1;
    minsInit[tid] = 0x7F7FFFFFu;   // FLT_MAX (uint order == float order)
}

// ---- main: half-B MFMA scan; fused 4-MFMA asm unit ----
__global__ __launch_bounds__(256, 4) void chamfer_main(
    const float* __restrict__ points, const float* __restrict__ gts,
    const unsigned short* __restrict__ pk, unsigned* __restrict__ minsU)
{
    const int d      = blockIdx.x;        // 0..1023
    const int group  = d & 63;            // (dir,b) — members share XCD (mod 8)
    const int member = (d >> 6) & 7;      // A-chunk 0..7 (512 points each)
    const int chunk  = d >> 9;            // B-half 0..1
    const int dir = group >> 5;
    const int b   = group & 31;

    const float* Ab = (dir ? gts : points) + (size_t)b * NPTS * 3;
    const int w = threadIdx.x >> 6, l = threadIdx.x & 63;
    const int half = l >> 5, c = l & 31;

    // pinned fragments (mfma B operand) — packing identical to verified R5..R26
    short8 af[S];
    #pragma unroll
    for (int s = 0; s < S; ++s) {
        const int i = member * 512 + w * 128 + s * 32 + c;
        const float ax = Ab[i * 3 + 0], ay = Ab[i * 3 + 1], az = Ab[i * 3 + 2];
        const float ha = ax * ax + ay * ay + az * az;
        unsigned short xh, xl, yh, yl, zh, zl, hh, hl;
        bf_split(-2.f * ax, xh, xl);
        bf_split(-2.f * ay, yh, yl);
        bf_split(-2.f * az, zh, zl);
        bf_split(ha, hh, hl);
        const unsigned short ONE = 0x3F80;
        short8 f;
        if (half == 0) {
            f[0]=(short)xh; f[1]=(short)yh; f[2]=(short)zh; f[3]=(short)hh;
            f[4]=(short)ONE; f[5]=(short)xh; f[6]=(short)yh; f[7]=(short)zh;
        } else {
            f[0]=(short)hh; f[1]=(short)ONE; f[2]=(short)xl; f[3]=(short)yl;
            f[4]=(short)zl; f[5]=(short)hl; f[6]=0; f[7]=0;
        }
        af[s] = f;
    }

    // streamed records: this block's half of the B cloud
    const unsigned short* rec =
        pk + (((size_t)(dir ^ 1) * NB + b) * NPTS + (size_t)chunk * BPTS + c) * 16
           + half * 8;

    float mm[S] = {1e30f, 1e30f, 1e30f, 1e30f};

#define TREE3(A, MM)                                                           \
    {                                                                          \
        float t0, t1, t2, t3, t4, u0, u1;                                      \
        asm("v_min3_f32 %0, %1, %2, %3" : "=v"(t0)                             \
            : "v"((A)[0]),  "v"((A)[1]),  "v"((A)[2]));                        \
        asm("v_min3_f32 %0, %1, %2, %3" : "=v"(t1)                             \
            : "v"((A)[3]),  "v"((A)[4]),  "v"((A)[5]));                        \
        asm("v_min3_f32 %0, %1, %2, %3" : "=v"(t2)                             \
            : "v"((A)[6]),  "v"((A)[7]),  "v"((A)[8]));                        \
        asm("v_min3_f32 %0, %1, %2, %3" : "=v"(t3)                             \
            : "v"((A)[9]),  "v"((A)[10]), "v"((A)[11]));                       \
        asm("v_min3_f32 %0, %1, %2, %3" : "=v"(t4)                             \
            : "v"((A)[12]), "v"((A)[13]), "v"((A)[14]));                       \
        asm("v_min3_f32 %0, %1, %2, %3" : "=v"(u0)                             \
            : "v"(t0), "v"(t1), "v"(t2));                                      \
        asm("v_min3_f32 %0, %1, %2, %3" : "=v"(u1)                             \
            : "v"(t3), "v"(t4), "v"((A)[15]));                                 \
        asm("v_min3_f32 %0, %0, %1, %2" : "+v"(MM)                             \
            : "v"(u0), "v"(u1));                                               \
    }

    // Four MFMAs in ONE asm block (inline-constant C=0, no zc), one shared
    // 40-state nop group (R24/R25/R26-verified hazard margin), then 4 trees.
    // Fixed per-unit cost (loads/loop/nops) amortized over 2x matrix work.
#define UNIT(REG)                                                              \
    {                                                                          \
        f32x16 a0, a1, a2, a3;                                                 \
        asm volatile(                                                          \
            "v_mfma_f32_32x32x16_bf16 %0, %4, %5, 0\n\t"                       \
            "v_mfma_f32_32x32x16_bf16 %1, %4, %6, 0\n\t"                       \
            "v_mfma_f32_32x32x16_bf16 %2, %4, %7, 0\n\t"                       \
            "v_mfma_f32_32x32x16_bf16 %3, %4, %8, 0\n\t"                       \
            "s_nop 7\n\t"                                                      \
            "s_nop 7\n\t"                                                      \
            "s_nop 7\n\t"                                                      \
            "s_nop 7\n\t"                                                      \
            "s_nop 7"                                                          \
            : "=&v"(a0), "=&v"(a1), "=&v"(a2), "=&v"(a3)                       \
            : "v"(REG), "v"(af[0]), "v"(af[1]), "v"(af[2]), "v"(af[3]));       \
        TREE3(a0, mm[0])                                                       \
        TREE3(a1, mm[1])                                                       \
        TREE3(a2, mm[2])                                                       \
        TREE3(a3, mm[3])                                                       \
        __builtin_amdgcn_sched_barrier(0);                                     \
    }

#define LD(I) (*(const short8*)(rec + (size_t)((I) < NT ? (I) : NT - 1) * 512))

    // static 3-buffer, 3-deep prefetch: zero rotation movs by construction
    short8 b0 = LD(0);
    short8 b1 = LD(1);
    short8 b2 = LD(2);

    #pragma unroll 1
    for (int t = 0; t < NT - 2; t += 3) {
        UNIT(b0) b0 = LD(t + 3);
        UNIT(b1) b1 = LD(t + 4);
        UNIT(b2) b2 = LD(t + 5);
    }
    // tail: NT = 64 = 3*21 + 1 -> loop covered units 0..62; one unit left
    UNIT(b0)
#undef LD
#undef UNIT
#undef TREE3

    // combine halves, clamp, atomicMin (2 writers per a-point; ~1 us, R22)
    #pragma unroll
    for (int s = 0; s < S; ++s) {
        float v = fminf(mm[s], __shfl_xor(mm[s], 32));
        v = fmaxf(v, 0.f);                      // uint-order == float-order
        if (half == 0) {
            const int ap = member * 512 + w * 128 + s * 32 + c;
            atomicMin(&minsU[(size_t)group * NPTS + ap], __float_as_uint(v));
        }
    }
}

// ---- pass 2: one block per (dir,b) group; 128 total d_out atomics ----
__global__ __launch_bounds__(256) void reduce_kernel(
    const float* __restrict__ mins, float* __restrict__ outp)
{
    const int group = blockIdx.x;          // 0..63
    const int dir   = group >> 5;
    const float* gm = mins + (size_t)group * NPTS;

    float local = 0.f;
    #pragma unroll
    for (int i = 0; i < NPTS / 256; ++i)
        local += sqrtf(gm[threadIdx.x + i * 256]);

    for (int off = 32; off > 0; off >>= 1)
        local += __shfl_down(local, off);
    __shared__ float wsum[4];
    const int w = threadIdx.x >> 6, l = threadIdx.x & 63;
    if (l == 0) wsum[w] = local;
    __syncthreads();
    if (threadIdx.x == 0) {
        const float s = (wsum[0] + wsum[1] + wsum[2] + wsum[3]) * SCALE;
        atomicAdd(&outp[0], s);          // p2g + g2p
        atomicAdd(&outp[1 + dir], s);    // out[1]=p2g, out[2]=g2p
    }
}

extern "C" void kernel_launch(void* const* d_in, const int* in_sizes, int n_in,
                              void* d_out, int out_size, void* d_ws, size_t ws_size,
                              hipStream_t stream) {
    const float* points = (const float*)d_in[0];   // [32][4096][3]
    const float* gts    = (const float*)d_in[1];   // [32][4096][3]
    float* outp = (float*)d_out;

    unsigned short* packed = (unsigned short*)((char*)d_ws + 64);   // 8 MB
    unsigned* mins = (unsigned*)((char*)d_ws + 64 + 8388608);       // 1 MB

    pack_kernel<<<1024, 256, 0, stream>>>(points, gts, packed, mins, outp);
    chamfer_main<<<1024, 256, 0, stream>>>(points, gts, packed, mins);
    reduce_kernel<<<64, 256, 0, stream>>>((const float*)mins, outp);
}